// Round 1
// baseline (274.917 us; speedup 1.0000x reference)
//
#include <hip/hip_runtime.h>
#include <hip/hip_bf16.h>

#define BQ 2
#define SEQ 2048
#define DM 1024
#define NH 16
#define DHEAD 64

typedef unsigned short u16;
typedef __attribute__((ext_vector_type(8))) short short8;   // 8 bf16 = 4 VGPRs
typedef __attribute__((ext_vector_type(4))) float f32x4;    // MFMA C/D frag

__device__ __forceinline__ u16 f2b(float f) {
    unsigned u = __builtin_bit_cast(unsigned, f);
    unsigned r = u + 0x7fffu + ((u >> 16) & 1u);   // RNE
    return (u16)(r >> 16);
}

// ---------------- prep kernels ----------------

__global__ __launch_bounds__(256) void cvt_x_kernel(const float* __restrict__ x,
                                                    u16* __restrict__ xb) {
    int i = blockIdx.x * 256 + threadIdx.x;       // one float4 per thread
    float4 v = ((const float4*)x)[i];
    ushort4 o;
    o.x = f2b(v.x); o.y = f2b(v.y); o.z = f2b(v.z); o.w = f2b(v.w);
    ((ushort4*)xb)[i] = o;
}

// W[k][d] f32 -> Wt[which*1024 + d][k] bf16   (n-major packed weights)
__global__ __launch_bounds__(256) void pack_w_kernel(const float* __restrict__ w,
                                                     u16* __restrict__ wt, int which) {
    int t = blockIdx.x * 256 + threadIdx.x;       // 262144 threads, 4 d-elems each
    int k = t >> 8;
    int d0 = (t & 255) * 4;
    float4 v = *(const float4*)(w + (size_t)k * DM + d0);
    size_t base = (size_t)(which * DM);
    wt[(base + d0 + 0) * DM + k] = f2b(v.x);
    wt[(base + d0 + 1) * DM + k] = f2b(v.y);
    wt[(base + d0 + 2) * DM + k] = f2b(v.z);
    wt[(base + d0 + 3) * DM + k] = f2b(v.w);
}

__global__ __launch_bounds__(256) void pack_bias_kernel(const float* __restrict__ b0,
                                                        const float* __restrict__ b1,
                                                        const float* __restrict__ b2,
                                                        const float* __restrict__ b3,
                                                        float* __restrict__ bias) {
    int i = blockIdx.x * 256 + threadIdx.x;       // 0..4095
    const float* s = (i < 1024) ? b0 : (i < 2048) ? b1 : (i < 3072) ? b2 : b3;
    bias[i] = s[i & 1023];
}

__global__ __launch_bounds__(256) void calc_len_kernel(const int* __restrict__ mask,
                                                       int* __restrict__ lengths) {
    __shared__ int cnt[BQ];
    if (threadIdx.x < BQ) cnt[threadIdx.x] = 0;
    __syncthreads();
    for (int b = 0; b < BQ; b++) {
        int c = 0;
        for (int s = threadIdx.x; s < SEQ; s += 256)
            c += (mask[b * SEQ + s] != 0) ? 1 : 0;
        atomicAdd(&cnt[b], c);
    }
    __syncthreads();
    if (threadIdx.x < BQ) lengths[threadIdx.x] = cnt[threadIdx.x];
}

// ---------------- fused QKVR GEMM ----------------
// Y[m][n] = sum_k xb[m][k] * wt[n][k] + bias[n];  M=4096, N=4096, K=1024
// n>>10 selects q/k/v/r destination.

__global__ __launch_bounds__(256) void gemm_qkvr(
        const u16* __restrict__ xb, const u16* __restrict__ wt,
        const float* __restrict__ bias,
        u16* __restrict__ qbuf, u16* __restrict__ kbuf, u16* __restrict__ vbuf,
        float* __restrict__ out) {
    __shared__ __align__(16) u16 As[128 * 40];
    __shared__ __align__(16) u16 Bs[128 * 40];
    const int tid = threadIdx.x;
    const int wid = tid >> 6, lane = tid & 63;
    const int lr = lane & 15, lg = lane >> 4;
    const int bm = blockIdx.x, bn = blockIdx.y;
    const int wm = (wid >> 1) * 64, wn = (wid & 1) * 64;

    f32x4 acc[4][4] = {};

    for (int kk = 0; kk < DM; kk += 32) {
        #pragma unroll
        for (int i = 0; i < 2; i++) {
            int c = tid + i * 256;                 // 512 chunks of 8 bf16
            int row = c >> 2, col = (c & 3) * 8;
            uint4 da = *(const uint4*)(xb + (size_t)(bm * 128 + row) * DM + kk + col);
            *(uint4*)(As + row * 40 + col) = da;
            uint4 db = *(const uint4*)(wt + (size_t)(bn * 128 + row) * DM + kk + col);
            *(uint4*)(Bs + row * 40 + col) = db;
        }
        __syncthreads();
        short8 af[4], bfr[4];
        #pragma unroll
        for (int mt = 0; mt < 4; mt++)
            af[mt] = *(const short8*)(As + (wm + mt * 16 + lr) * 40 + lg * 8);
        #pragma unroll
        for (int nt = 0; nt < 4; nt++)
            bfr[nt] = *(const short8*)(Bs + (wn + nt * 16 + lr) * 40 + lg * 8);
        #pragma unroll
        for (int mt = 0; mt < 4; mt++)
            #pragma unroll
            for (int nt = 0; nt < 4; nt++)
                acc[mt][nt] = __builtin_amdgcn_mfma_f32_16x16x32_bf16(
                        af[mt], bfr[nt], acc[mt][nt], 0, 0, 0);
        __syncthreads();
    }

    // epilogue: C/D layout col=lane&15, row=(lane>>4)*4+reg
    #pragma unroll
    for (int nt = 0; nt < 4; nt++) {
        int n = bn * 128 + wn + nt * 16 + lr;
        int which = n >> 10, d = n & 1023;
        float bv_ = bias[n];
        #pragma unroll
        for (int mt = 0; mt < 4; mt++) {
            #pragma unroll
            for (int r = 0; r < 4; r++) {
                int m = bm * 128 + wm + mt * 16 + lg * 4 + r;   // = b*SEQ + s
                float y = acc[mt][nt][r] + bv_;
                if (which == 3) {
                    out[(size_t)m * DM + d] = y;
                } else {
                    int h = d >> 6, dh = d & 63;
                    int b = m >> 11, s = m & (SEQ - 1);
                    size_t idx = ((size_t)(b * NH + h) * SEQ + s) * DHEAD + dh;
                    u16 hv = f2b(y);
                    if (which == 0) qbuf[idx] = hv;
                    else if (which == 1) kbuf[idx] = hv;
                    else vbuf[idx] = hv;
                }
            }
        }
    }
}

// ---------------- flash attention (causal; rows >= len skipped) ----------------
// grid: (S/64 q-tiles, B*H). block: 256 = 4 waves x 16 q-rows.

__global__ __launch_bounds__(256) void attn_kernel(
        const u16* __restrict__ qbuf, const u16* __restrict__ kbuf,
        const u16* __restrict__ vbuf, const int* __restrict__ lengths,
        float* __restrict__ out) {
    __shared__ __align__(16) u16 P[4][16][80];
    __shared__ __align__(16) u16 Vt[64][80];

    const int qt = blockIdx.x, bh = blockIdx.y;
    const int b = bh >> 4, h = bh & 15;
    const int len = lengths[b];
    const int qbase = qt * 64;
    if (qbase >= len) return;

    const int tid = threadIdx.x, wid = tid >> 6, lane = tid & 63;
    const int lr = lane & 15, lg = lane >> 4;

    const u16* qp = qbuf + (size_t)bh * SEQ * DHEAD;
    const u16* kp = kbuf + (size_t)bh * SEQ * DHEAD;
    const u16* vp = vbuf + (size_t)bh * SEQ * DHEAD;

    const int qrow = qbase + wid * 16;
    short8 aq0 = *(const short8*)(qp + (size_t)(qrow + lr) * DHEAD + lg * 8);
    short8 aq1 = *(const short8*)(qp + (size_t)(qrow + lr) * DHEAD + 32 + lg * 8);

    f32x4 oacc[4] = {};
    float mrow[4], lsum[4];
    #pragma unroll
    for (int r = 0; r < 4; r++) { mrow[r] = -3.0e38f; lsum[r] = 0.0f; }

    for (int kt = 0; kt <= qt; kt++) {
        const int kbase = kt * 64;
        // stage V^T into LDS (cooperative, all waves)
        #pragma unroll
        for (int i = 0; i < 2; i++) {
            int c = tid + i * 256;                // key=c>>3, dh0=(c&7)*8
            int key = c >> 3, dh0 = (c & 7) * 8;
            union { uint4 q; u16 s[8]; } u;
            u.q = *(const uint4*)(vp + (size_t)(kbase + key) * DHEAD + dh0);
            #pragma unroll
            for (int j = 0; j < 8; j++) Vt[dh0 + j][key] = u.s[j];
        }
        // QK^T (global K reads, no LDS dependency)
        f32x4 sc[4] = {};
        #pragma unroll
        for (int nt = 0; nt < 4; nt++) {
            short8 bk0 = *(const short8*)(kp + (size_t)(kbase + nt * 16 + lr) * DHEAD + lg * 8);
            short8 bk1 = *(const short8*)(kp + (size_t)(kbase + nt * 16 + lr) * DHEAD + 32 + lg * 8);
            sc[nt] = __builtin_amdgcn_mfma_f32_16x16x32_bf16(aq0, bk0, sc[nt], 0, 0, 0);
            sc[nt] = __builtin_amdgcn_mfma_f32_16x16x32_bf16(aq1, bk1, sc[nt], 0, 0, 0);
        }
        __syncthreads();   // Vt ready

        // softmax (online), D-layout: row=lg*4+r, col=nt*16+lr
        float pv[4][4];
        const bool diag = (kt == qt);
        #pragma unroll
        for (int nt = 0; nt < 4; nt++)
            #pragma unroll
            for (int r = 0; r < 4; r++) {
                float s = sc[nt][r] * 0.125f;      // 1/sqrt(64)
                if (diag) {
                    int key = kbase + nt * 16 + lr;
                    int q = qbase + wid * 16 + lg * 4 + r;
                    if (key > q) s = -3.0e38f;
                }
                pv[nt][r] = s;
            }
        #pragma unroll
        for (int r = 0; r < 4; r++) {
            float m = fmaxf(fmaxf(pv[0][r], pv[1][r]), fmaxf(pv[2][r], pv[3][r]));
            #pragma unroll
            for (int off = 1; off < 16; off <<= 1)
                m = fmaxf(m, __shfl_xor(m, off, 64));
            float mnew = fmaxf(mrow[r], m);
            float scl = __expf(mrow[r] - mnew);
            mrow[r] = mnew;
            float ps = 0.0f;
            #pragma unroll
            for (int nt = 0; nt < 4; nt++) {
                float p = __expf(pv[nt][r] - mnew);
                pv[nt][r] = p; ps += p;
            }
            #pragma unroll
            for (int off = 1; off < 16; off <<= 1)
                ps += __shfl_xor(ps, off, 64);
            lsum[r] = lsum[r] * scl + ps;
            #pragma unroll
            for (int nt = 0; nt < 4; nt++) oacc[nt][r] *= scl;
        }
        // P -> LDS (bf16, per-wave region; same-wave write->read is in order)
        #pragma unroll
        for (int nt = 0; nt < 4; nt++)
            #pragma unroll
            for (int r = 0; r < 4; r++)
                P[wid][lg * 4 + r][nt * 16 + lr] = f2b(pv[nt][r]);

        short8 ap0 = *(const short8*)(&P[wid][lr][lg * 8]);
        short8 ap1 = *(const short8*)(&P[wid][lr][32 + lg * 8]);
        #pragma unroll
        for (int nt = 0; nt < 4; nt++) {
            short8 bv0 = *(const short8*)(&Vt[nt * 16 + lr][lg * 8]);
            short8 bv1 = *(const short8*)(&Vt[nt * 16 + lr][32 + lg * 8]);
            oacc[nt] = __builtin_amdgcn_mfma_f32_16x16x32_bf16(ap0, bv0, oacc[nt], 0, 0, 0);
            oacc[nt] = __builtin_amdgcn_mfma_f32_16x16x32_bf16(ap1, bv1, oacc[nt], 0, 0, 0);
        }
        __syncthreads();   // Vt consumed before next-iter overwrite
    }

    #pragma unroll
    for (int nt = 0; nt < 4; nt++) {
        #pragma unroll
        for (int r = 0; r < 4; r++) {
            int q = qbase + wid * 16 + lg * 4 + r;
            if (q < len) {
                size_t idx = ((size_t)b * SEQ + q) * DM + h * DHEAD + nt * 16 + lr;
                out[idx] += oacc[nt][r] / lsum[r];
            }
        }
    }
}

// ---------------- launch ----------------

extern "C" void kernel_launch(void* const* d_in, const int* in_sizes, int n_in,
                              void* d_out, int out_size, void* d_ws, size_t ws_size,
                              hipStream_t stream) {
    const float* x  = (const float*)d_in[0];
    const int*  mask = (const int*)d_in[1];
    const float* Wq = (const float*)d_in[2];
    const float* bq = (const float*)d_in[3];
    const float* Wk = (const float*)d_in[4];
    const float* bk = (const float*)d_in[5];
    const float* Wv = (const float*)d_in[6];
    const float* bv = (const float*)d_in[7];
    const float* Wr = (const float*)d_in[8];
    const float* br = (const float*)d_in[9];
    float* out = (float*)d_out;

    char* ws = (char*)d_ws;
    size_t off = 0;
    auto alloc = [&](size_t bytes) {
        size_t o = off; off = (off + bytes + 255) & ~(size_t)255; return o;
    };
    u16* xb   = (u16*)(ws + alloc((size_t)BQ * SEQ * DM * 2));
    u16* wt   = (u16*)(ws + alloc((size_t)4 * DM * DM * 2));
    float* bias = (float*)(ws + alloc(4 * DM * 4));
    u16* qbuf = (u16*)(ws + alloc((size_t)BQ * NH * SEQ * DHEAD * 2));
    u16* kbuf = (u16*)(ws + alloc((size_t)BQ * NH * SEQ * DHEAD * 2));
    u16* vbuf = (u16*)(ws + alloc((size_t)BQ * NH * SEQ * DHEAD * 2));
    int* lens = (int*)(ws + alloc(256));

    hipLaunchKernelGGL(cvt_x_kernel, dim3((BQ * SEQ * DM) / 4 / 256), dim3(256), 0, stream, x, xb);
    hipLaunchKernelGGL(pack_w_kernel, dim3(DM * DM / 4 / 256), dim3(256), 0, stream, Wq, wt, 0);
    hipLaunchKernelGGL(pack_w_kernel, dim3(DM * DM / 4 / 256), dim3(256), 0, stream, Wk, wt, 1);
    hipLaunchKernelGGL(pack_w_kernel, dim3(DM * DM / 4 / 256), dim3(256), 0, stream, Wv, wt, 2);
    hipLaunchKernelGGL(pack_w_kernel, dim3(DM * DM / 4 / 256), dim3(256), 0, stream, Wr, wt, 3);
    hipLaunchKernelGGL(pack_bias_kernel, dim3(16), dim3(256), 0, stream, bq, bk, bv, br, bias);
    hipLaunchKernelGGL(calc_len_kernel, dim3(1), dim3(256), 0, stream, mask, lens);
    hipLaunchKernelGGL(gemm_qkvr, dim3(32, 32), dim3(256), 0, stream,
                       xb, wt, bias, qbuf, kbuf, vbuf, out);
    hipLaunchKernelGGL(attn_kernel, dim3(SEQ / 64, BQ * NH), dim3(256), 0, stream,
                       qbuf, kbuf, vbuf, lens, out);
}

// Round 2
// 171.969 us; speedup vs baseline: 1.5986x; 1.5986x over previous
//
#include <hip/hip_runtime.h>
#include <hip/hip_bf16.h>

#define BQ 2
#define SEQ 2048
#define DM 1024
#define NH 16
#define DHEAD 64

typedef unsigned short u16;
typedef unsigned int u32;
typedef __attribute__((ext_vector_type(8))) short short8;   // 8 bf16 = 4 VGPRs
typedef __attribute__((ext_vector_type(4))) float f32x4;    // MFMA C/D frag

__device__ __forceinline__ u16 f2b(float f) {
    unsigned u = __builtin_bit_cast(unsigned, f);
    unsigned r = u + 0x7fffu + ((u >> 16) & 1u);   // RNE
    return (u16)(r >> 16);
}

__device__ __forceinline__ void gld_lds16(const void* g, void* l) {
    __builtin_amdgcn_global_load_lds(
        (const __attribute__((address_space(1))) void*)g,
        (__attribute__((address_space(3))) void*)l, 16, 0, 0);
}

// ---------------- prep kernels ----------------

__global__ __launch_bounds__(256) void cvt_x_kernel(const float* __restrict__ x,
                                                    u16* __restrict__ xb) {
    int i = blockIdx.x * 256 + threadIdx.x;       // one float4 per thread
    float4 v = ((const float4*)x)[i];
    ushort4 o;
    o.x = f2b(v.x); o.y = f2b(v.y); o.z = f2b(v.z); o.w = f2b(v.w);
    ((ushort4*)xb)[i] = o;
}

// fused 4-weight transpose: W[k][d] f32 -> wt[wsel*1024 + d][k] bf16
__global__ __launch_bounds__(256) void pack_w4(
        const float* __restrict__ W0, const float* __restrict__ W1,
        const float* __restrict__ W2, const float* __restrict__ W3,
        u16* __restrict__ wt) {
    __shared__ u16 Ws[64][68];
    const float* W = (blockIdx.z == 0) ? W0 : (blockIdx.z == 1) ? W1
                   : (blockIdx.z == 2) ? W2 : W3;
    const int k0 = blockIdx.x * 64, d0 = blockIdx.y * 64;
    const int t = threadIdx.x;
    const int lrow = t >> 4, lcol = (t & 15) * 4;
    #pragma unroll
    for (int i = 0; i < 4; i++) {
        float4 v = *(const float4*)(W + (size_t)(k0 + lrow + i * 16) * DM + d0 + lcol);
        Ws[lrow + i * 16][lcol + 0] = f2b(v.x);
        Ws[lrow + i * 16][lcol + 1] = f2b(v.y);
        Ws[lrow + i * 16][lcol + 2] = f2b(v.z);
        Ws[lrow + i * 16][lcol + 3] = f2b(v.w);
    }
    __syncthreads();
    const int dl = t >> 2, kq = (t & 3) * 16;
    uint4 o1, o2;
    o1.x = (u32)Ws[kq + 0][dl]  | ((u32)Ws[kq + 1][dl]  << 16);
    o1.y = (u32)Ws[kq + 2][dl]  | ((u32)Ws[kq + 3][dl]  << 16);
    o1.z = (u32)Ws[kq + 4][dl]  | ((u32)Ws[kq + 5][dl]  << 16);
    o1.w = (u32)Ws[kq + 6][dl]  | ((u32)Ws[kq + 7][dl]  << 16);
    o2.x = (u32)Ws[kq + 8][dl]  | ((u32)Ws[kq + 9][dl]  << 16);
    o2.y = (u32)Ws[kq + 10][dl] | ((u32)Ws[kq + 11][dl] << 16);
    o2.z = (u32)Ws[kq + 12][dl] | ((u32)Ws[kq + 13][dl] << 16);
    o2.w = (u32)Ws[kq + 14][dl] | ((u32)Ws[kq + 15][dl] << 16);
    u16* dst = wt + (size_t)(blockIdx.z * DM + d0 + dl) * DM + k0 + kq;
    *(uint4*)(dst) = o1;
    *(uint4*)(dst + 8) = o2;
}

__global__ __launch_bounds__(256) void pack_bias_kernel(const float* __restrict__ b0,
                                                        const float* __restrict__ b1,
                                                        const float* __restrict__ b2,
                                                        const float* __restrict__ b3,
                                                        float* __restrict__ bias) {
    int i = blockIdx.x * 256 + threadIdx.x;       // 0..4095
    const float* s = (i < 1024) ? b0 : (i < 2048) ? b1 : (i < 3072) ? b2 : b3;
    bias[i] = s[i & 1023];
}

__global__ __launch_bounds__(256) void calc_len_kernel(const int* __restrict__ mask,
                                                       int* __restrict__ lengths) {
    __shared__ int cnt[BQ];
    if (threadIdx.x < BQ) cnt[threadIdx.x] = 0;
    __syncthreads();
    for (int b = 0; b < BQ; b++) {
        int c = 0;
        for (int s = threadIdx.x; s < SEQ; s += 256)
            c += (mask[b * SEQ + s] != 0) ? 1 : 0;
        atomicAdd(&cnt[b], c);
    }
    __syncthreads();
    if (threadIdx.x < BQ) lengths[threadIdx.x] = cnt[threadIdx.x];
}

// ---------------- fused QKVR GEMM (m97 pattern: global_load_lds) ----------------
// Y[m][n] = sum_k xb[m][k] * wt[n][k] + bias[n];  M=4096, N=4096, K=1024

__global__ __launch_bounds__(256) void gemm_qkvr(
        const u16* __restrict__ xb, const u16* __restrict__ wt,
        const float* __restrict__ bias,
        u16* __restrict__ qbuf, u16* __restrict__ kbuf, u16* __restrict__ vbuf,
        float* __restrict__ out) {
    __shared__ __align__(16) u16 As[128 * 32];
    __shared__ __align__(16) u16 Bs[128 * 32];
    const int tid = threadIdx.x;
    const int wid = tid >> 6, lane = tid & 63;
    const int lr = lane & 15, lg = lane >> 4;
    const int bm = blockIdx.x, bn = blockIdx.y;
    const int wm = (wid >> 1) * 64, wn = (wid & 1) * 64;

    // staging: chunk c = wid*2+i covers rows [c*16, c*16+16), lane l -> row c*16+(l>>2), col (l&3)*8 u16
    const int crow = lane >> 2, ccol = (lane & 3) * 8;
    const u16* agp0 = xb + (size_t)(bm * 128 + (wid * 2 + 0) * 16 + crow) * DM + ccol;
    const u16* agp1 = xb + (size_t)(bm * 128 + (wid * 2 + 1) * 16 + crow) * DM + ccol;
    const u16* bgp0 = wt + (size_t)(bn * 128 + (wid * 2 + 0) * 16 + crow) * DM + ccol;
    const u16* bgp1 = wt + (size_t)(bn * 128 + (wid * 2 + 1) * 16 + crow) * DM + ccol;
    u16* al0 = As + (wid * 2 + 0) * 512;
    u16* al1 = As + (wid * 2 + 1) * 512;
    u16* bl0 = Bs + (wid * 2 + 0) * 512;
    u16* bl1 = Bs + (wid * 2 + 1) * 512;

    f32x4 acc[4][4] = {};

    for (int kk = 0; kk < DM; kk += 32) {
        gld_lds16(agp0 + kk, al0);
        gld_lds16(agp1 + kk, al1);
        gld_lds16(bgp0 + kk, bl0);
        gld_lds16(bgp1 + kk, bl1);
        __syncthreads();   // drains vmcnt -> staged data visible
        short8 af[4], bfr[4];
        #pragma unroll
        for (int mt = 0; mt < 4; mt++)
            af[mt] = *(const short8*)(As + (wm + mt * 16 + lr) * 32 + lg * 8);
        #pragma unroll
        for (int nt = 0; nt < 4; nt++)
            bfr[nt] = *(const short8*)(Bs + (wn + nt * 16 + lr) * 32 + lg * 8);
        #pragma unroll
        for (int mt = 0; mt < 4; mt++)
            #pragma unroll
            for (int nt = 0; nt < 4; nt++)
                acc[mt][nt] = __builtin_amdgcn_mfma_f32_16x16x32_bf16(
                        af[mt], bfr[nt], acc[mt][nt], 0, 0, 0);
        __syncthreads();   // all reads done before next stage overwrites
    }

    // epilogue: C/D layout col=lane&15 (n), row=(lane>>4)*4+reg (m)
    #pragma unroll
    for (int nt = 0; nt < 4; nt++) {
        int n = bn * 128 + wn + nt * 16 + lr;
        int which = n >> 10, d = n & 1023;
        float bv_ = bias[n];
        #pragma unroll
        for (int mt = 0; mt < 4; mt++) {
            #pragma unroll
            for (int r = 0; r < 4; r++) {
                int m = bm * 128 + wm + mt * 16 + lg * 4 + r;   // = b*SEQ + s
                float y = acc[mt][nt][r] + bv_;
                if (which == 3) {
                    out[(size_t)m * DM + d] = y;
                } else {
                    int h = d >> 6, dh = d & 63;
                    int b = m >> 11, s = m & (SEQ - 1);
                    size_t idx = ((size_t)(b * NH + h) * SEQ + s) * DHEAD + dh;
                    u16 hv = f2b(y);
                    if (which == 0) qbuf[idx] = hv;
                    else if (which == 1) kbuf[idx] = hv;
                    else vbuf[idx] = hv;
                }
            }
        }
    }
}

// ---------------- flash attention v2 ----------------
// Swapped QK^T (S^T = mfma(K,Q)) and swapped PV (O^T = mfma(Vt,P)):
// softmax stats and O-rescale are in-lane (q = lane&15 per 16-q tile).
// Block: 256 thr = 4 waves x 32 q-rows = 128 q-rows. KV tile = 64.
// LDS: Vt[64 d][64 keys] and per-wave P[32 q][64 keys], both bf16-pair words
// with XOR swizzle word ^= ((row&7)<<2)  (writes 2-way=free, b128 reads optimal).

__global__ __launch_bounds__(256) void attn_kernel(
        const u16* __restrict__ qbuf, const u16* __restrict__ kbuf,
        const u16* __restrict__ vbuf, const int* __restrict__ lengths,
        float* __restrict__ out) {
    __shared__ __align__(16) u32 Vt[64 * 32];
    __shared__ __align__(16) u32 Pl[4][32 * 32];

    const int qt = blockIdx.x, bh = blockIdx.y;
    const int b = bh >> 4, h = bh & 15;
    const int len = lengths[b];
    const int qbase = qt * 128;
    if (qbase >= len) return;

    const int tid = threadIdx.x, wid = tid >> 6, lane = tid & 63;
    const int lr = lane & 15, lg = lane >> 4;
    const int qw = qbase + wid * 32;              // wave's first q row
    const int swz = (lr & 7) << 2;

    const u16* qp = qbuf + (size_t)bh * SEQ * DHEAD;
    const u16* kp = kbuf + (size_t)bh * SEQ * DHEAD;
    const u16* vp = vbuf + (size_t)bh * SEQ * DHEAD;

    // Q B-frags held in registers the whole kernel
    short8 bq[2][2];
    #pragma unroll
    for (int ntq = 0; ntq < 2; ntq++)
        #pragma unroll
        for (int ks = 0; ks < 2; ks++)
            bq[ntq][ks] = *(const short8*)(qp + (size_t)(qw + ntq * 16 + lr) * DHEAD + ks * 32 + lg * 8);

    f32x4 oacc[4][2] = {};
    float mrow[2] = {-3.0e38f, -3.0e38f};
    float lsum[2] = {0.0f, 0.0f};

    const int nkt = 2 * qt + 2;
    const int vk = (tid & 31) * 2, vd = (tid >> 5) * 8;   // V staging assignment

    for (int kt = 0; kt < nkt; kt++) {
        const int kbase = kt * 64;
        const bool active  = (kbase <= qw + 31);
        const bool maskful = (kbase + 63 > qw);

        // V loads early (latency hidden under QK + softmax)
        const u16* vrow = vp + (size_t)(kbase + vk) * DHEAD + vd;
        uint4 va = *(const uint4*)vrow;
        uint4 vb2 = *(const uint4*)(vrow + DHEAD);

        f32x4 sc[4][2] = {};
        float scl[2] = {1.0f, 1.0f};
        if (active) {
            // QK^T swapped: A = K rows (keys), B = Q rows -> D[key][q]
            #pragma unroll
            for (int mtk = 0; mtk < 4; mtk++) {
                #pragma unroll
                for (int ks = 0; ks < 2; ks++) {
                    short8 ak = *(const short8*)(kp + (size_t)(kbase + mtk * 16 + lr) * DHEAD + ks * 32 + lg * 8);
                    #pragma unroll
                    for (int ntq = 0; ntq < 2; ntq++)
                        sc[mtk][ntq] = __builtin_amdgcn_mfma_f32_16x16x32_bf16(
                                ak, bq[ntq][ks], sc[mtk][ntq], 0, 0, 0);
                }
            }
            // scale + causal mask; key = kbase+mtk*16+lg*4+r, q = qw+ntq*16+lr
            if (maskful) {
                #pragma unroll
                for (int mtk = 0; mtk < 4; mtk++) {
                    int keyb = kbase + mtk * 16 + lg * 4;
                    #pragma unroll
                    for (int ntq = 0; ntq < 2; ntq++) {
                        int qq = qw + ntq * 16 + lr;
                        #pragma unroll
                        for (int r = 0; r < 4; r++)
                            sc[mtk][ntq][r] = (keyb + r > qq) ? -3.0e38f
                                                              : sc[mtk][ntq][r] * 0.125f;
                    }
                }
            } else {
                #pragma unroll
                for (int mtk = 0; mtk < 4; mtk++)
                    #pragma unroll
                    for (int ntq = 0; ntq < 2; ntq++)
                        #pragma unroll
                        for (int r = 0; r < 4; r++)
                            sc[mtk][ntq][r] *= 0.125f;
            }
            // online softmax: in-lane 16 values + 2 shuffles (lanes lr+16*lg hold disjoint keys)
            #pragma unroll
            for (int ntq = 0; ntq < 2; ntq++) {
                float mx = sc[0][ntq][0];
                #pragma unroll
                for (int mtk = 0; mtk < 4; mtk++)
                    #pragma unroll
                    for (int r = 0; r < 4; r++)
                        mx = fmaxf(mx, sc[mtk][ntq][r]);
                mx = fmaxf(mx, __shfl_xor(mx, 16, 64));
                mx = fmaxf(mx, __shfl_xor(mx, 32, 64));
                float mnew = fmaxf(mrow[ntq], mx);
                float sq = __expf(mrow[ntq] - mnew);
                mrow[ntq] = mnew;
                float ps = 0.0f;
                #pragma unroll
                for (int mtk = 0; mtk < 4; mtk++)
                    #pragma unroll
                    for (int r = 0; r < 4; r++) {
                        float p = __expf(sc[mtk][ntq][r] - mnew);
                        sc[mtk][ntq][r] = p;
                        ps += p;
                    }
                ps += __shfl_xor(ps, 16, 64);
                ps += __shfl_xor(ps, 32, 64);
                lsum[ntq] = lsum[ntq] * sq + ps;
                scl[ntq] = sq;
            }
            // rescale O (in-lane: O^T col q = ntq*16+lr)
            #pragma unroll
            for (int mtd = 0; mtd < 4; mtd++)
                #pragma unroll
                for (int ntq = 0; ntq < 2; ntq++)
                    #pragma unroll
                    for (int r = 0; r < 4; r++)
                        oacc[mtd][ntq][r] *= scl[ntq];
        }

        __syncthreads();   // all waves finished PV-reading Vt(kt-1)

        // Vt writes: Vt[d][key] bf16-pairs, swizzled; key pair = (vk, vk+1)
        {
            union { uint4 v; u16 s[8]; } ua, ub;
            ua.v = va; ub.v = vb2;
            #pragma unroll
            for (int j = 0; j < 8; j++) {
                u32 w = (u32)ua.s[j] | ((u32)ub.s[j] << 16);
                Vt[(vd + j) * 32 + ((tid & 31) ^ (j << 2))] = w;
            }
        }
        // P writes (per-wave region): P[q][key] bf16-pairs, key pairs along r
        if (active) {
            #pragma unroll
            for (int ntq = 0; ntq < 2; ntq++) {
                int rowbase = (ntq * 16 + lr) * 32;
                #pragma unroll
                for (int mtk = 0; mtk < 4; mtk++)
                    #pragma unroll
                    for (int i = 0; i < 2; i++) {
                        u32 w = (u32)f2b(sc[mtk][ntq][2 * i])
                              | ((u32)f2b(sc[mtk][ntq][2 * i + 1]) << 16);
                        Pl[wid][rowbase + ((mtk * 8 + lg * 2 + i) ^ swz)] = w;
                    }
            }
        }

        __syncthreads();   // Vt(kt) ready

        // PV swapped: A = Vt rows (d), B = P rows (q) -> D[d][q] = O^T
        if (active) {
            #pragma unroll
            for (int ks = 0; ks < 2; ks++) {
                int wv = (ks * 16 + lg * 4) ^ swz;
                short8 bp0 = *(const short8*)&Pl[wid][(lr) * 32 + wv];
                short8 bp1 = *(const short8*)&Pl[wid][(16 + lr) * 32 + wv];
                #pragma unroll
                for (int mtd = 0; mtd < 4; mtd++) {
                    short8 av = *(const short8*)&Vt[(mtd * 16 + lr) * 32 + wv];
                    oacc[mtd][0] = __builtin_amdgcn_mfma_f32_16x16x32_bf16(av, bp0, oacc[mtd][0], 0, 0, 0);
                    oacc[mtd][1] = __builtin_amdgcn_mfma_f32_16x16x32_bf16(av, bp1, oacc[mtd][1], 0, 0, 0);
                }
            }
        }
    }

    // epilogue: O^T[d][q]: d = mtd*16+lg*4+r, q = ntq*16+lr (in-lane lsum)
    #pragma unroll
    for (int ntq = 0; ntq < 2; ntq++) {
        int q = qw + ntq * 16 + lr;
        if (q < len) {
            float inv = 1.0f / lsum[ntq];
            float* orow = out + (size_t)(b * SEQ + q) * DM + h * DHEAD;
            #pragma unroll
            for (int mtd = 0; mtd < 4; mtd++)
                #pragma unroll
                for (int r = 0; r < 4; r++)
                    orow[mtd * 16 + lg * 4 + r] += oacc[mtd][ntq][r] * inv;
        }
    }
}

// ---------------- launch ----------------

extern "C" void kernel_launch(void* const* d_in, const int* in_sizes, int n_in,
                              void* d_out, int out_size, void* d_ws, size_t ws_size,
                              hipStream_t stream) {
    const float* x  = (const float*)d_in[0];
    const int*  mask = (const int*)d_in[1];
    const float* Wq = (const float*)d_in[2];
    const float* bq = (const float*)d_in[3];
    const float* Wk = (const float*)d_in[4];
    const float* bk = (const float*)d_in[5];
    const float* Wv = (const float*)d_in[6];
    const float* bv = (const float*)d_in[7];
    const float* Wr = (const float*)d_in[8];
    const float* br = (const float*)d_in[9];
    float* out = (float*)d_out;

    char* ws = (char*)d_ws;
    size_t off = 0;
    auto alloc = [&](size_t bytes) {
        size_t o = off; off = (off + bytes + 255) & ~(size_t)255; return o;
    };
    u16* xb   = (u16*)(ws + alloc((size_t)BQ * SEQ * DM * 2));
    u16* wt   = (u16*)(ws + alloc((size_t)4 * DM * DM * 2));
    float* bias = (float*)(ws + alloc(4 * DM * 4));
    u16* qbuf = (u16*)(ws + alloc((size_t)BQ * NH * SEQ * DHEAD * 2));
    u16* kbuf = (u16*)(ws + alloc((size_t)BQ * NH * SEQ * DHEAD * 2));
    u16* vbuf = (u16*)(ws + alloc((size_t)BQ * NH * SEQ * DHEAD * 2));
    int* lens = (int*)(ws + alloc(256));

    hipLaunchKernelGGL(cvt_x_kernel, dim3((BQ * SEQ * DM) / 4 / 256), dim3(256), 0, stream, x, xb);
    hipLaunchKernelGGL(pack_w4, dim3(16, 16, 4), dim3(256), 0, stream, Wq, Wk, Wv, Wr, wt);
    hipLaunchKernelGGL(pack_bias_kernel, dim3(16), dim3(256), 0, stream, bq, bk, bv, br, bias);
    hipLaunchKernelGGL(calc_len_kernel, dim3(1), dim3(256), 0, stream, mask, lens);
    hipLaunchKernelGGL(gemm_qkvr, dim3(32, 32), dim3(256), 0, stream,
                       xb, wt, bias, qbuf, kbuf, vbuf, out);
    hipLaunchKernelGGL(attn_kernel, dim3(SEQ / 128, BQ * NH), dim3(256), 0, stream,
                       qbuf, kbuf, vbuf, lens, out);
}